// Round 1
// baseline (452.363 us; speedup 1.0000x reference)
//
#include <hip/hip_runtime.h>
#include <math.h>
#include <stdint.h>

#define NE 8
#define ED 1024
#define FD 2048
#define NTOK 2048
#define BM 128
#define BN 128
#define BK 64

typedef unsigned short u16;
typedef unsigned int u32;
typedef __attribute__((ext_vector_type(4))) float f32x4;
typedef __attribute__((ext_vector_type(8))) short s16x8;
typedef __attribute__((ext_vector_type(4))) unsigned int u32v4;

// ---------------- helpers ----------------

__device__ __forceinline__ u16 f2bf(float f) {
    u32 u = __builtin_bit_cast(u32, f);
    u32 r = u + 0x7fffu + ((u >> 16) & 1u);   // RNE
    return (u16)(r >> 16);
}

typedef __attribute__((address_space(1))) const void gvoid_t;
typedef __attribute__((address_space(3))) void lvoid_t;

__device__ __forceinline__ void gload16(const void* g, void* l) {
    // async global->LDS, 16B per lane; LDS dest = uniform base + lane*16
    __builtin_amdgcn_global_load_lds((gvoid_t*)g, (lvoid_t*)l, 16, 0, 0);
}

// workspace layout (bytes)
#define WS_CNT 0u
#define WS_OFF 64u
#define WS_TOK 256u
#define WS_WT  65792u
#define WS_XB  131328u
#define WS_WG  (8u << 20)
#define WS_WU  41943040u
#define WS_WD  75497472u
#define WS_ACT 109051904u
#define WS_NEED 130023424u

// ---------------- router ----------------

__global__ __launch_bounds__(256) void k_router(
        const float* __restrict__ gin, const float* __restrict__ gk,
        int* __restrict__ cnt, int* __restrict__ tok, float* __restrict__ wl) {
    int lane = threadIdx.x & 63;
    int t = (blockIdx.x * 256 + threadIdx.x) >> 6;   // one wave per token
    if (t >= NTOK) return;
    const float* row = gin + (size_t)t * ED;
    float acc[NE];
#pragma unroll
    for (int e = 0; e < NE; e++) acc[e] = 0.f;
    for (int i = lane; i < ED; i += 64) {
        float v = row[i];
        const float* g = gk + i * NE;
#pragma unroll
        for (int e = 0; e < NE; e++) acc[e] = fmaf(v, g[e], acc[e]);
    }
#pragma unroll
    for (int e = 0; e < NE; e++) {
#pragma unroll
        for (int off = 32; off > 0; off >>= 1)
            acc[e] += __shfl_down(acc[e], off, 64);
    }
    if (lane == 0) {
        int b0 = 0; float v0 = acc[0];
#pragma unroll
        for (int e = 1; e < NE; e++) if (acc[e] > v0) { v0 = acc[e]; b0 = e; }
        int b1 = -1; float v1 = -3.4e38f;
#pragma unroll
        for (int e = 0; e < NE; e++) if (e != b0 && acc[e] > v1) { v1 = acc[e]; b1 = e; }
        float w0 = 1.f / (1.f + __expf(-v0));
        float w1 = 1.f / (1.f + __expf(-v1));
        int p0 = atomicAdd(&cnt[b0], 1);
        tok[b0 * NTOK + p0] = t; wl[b0 * NTOK + p0] = w0;
        int p1 = atomicAdd(&cnt[b1], 1);
        tok[b1 * NTOK + p1] = t; wl[b1 * NTOK + p1] = w1;
    }
}

__global__ void k_scan(const int* __restrict__ cnt, int* __restrict__ off) {
    if (threadIdx.x == 0 && blockIdx.x == 0) {
        int a = 0;
#pragma unroll
        for (int e = 0; e < NE; e++) { off[e] = a; a += (cnt[e] + 127) & ~127; }
        off[NE] = a;
    }
}

// ---------------- x -> bf16 ----------------

__global__ __launch_bounds__(256) void k_cvtx(const float4* __restrict__ x, uint2* __restrict__ xb) {
    int i = blockIdx.x * 256 + threadIdx.x;   // over groups of 4 floats; total 524288
    float4 v = x[i];
    uint2 o;
    o.x = (u32)f2bf(v.x) | ((u32)f2bf(v.y) << 16);
    o.y = (u32)f2bf(v.z) | ((u32)f2bf(v.w) << 16);
    xb[i] = o;
}

// ---------------- weights f32 -> bf16, fragment-ordered tiles ----------------
// output image per (e,nt,kc): 8192 elems, layout [n(128)][k(64)], n-major, k contiguous

__global__ __launch_bounds__(256) void k_cvtw(
        const float* __restrict__ wgf, const float* __restrict__ wuf, const float* __restrict__ wdf,
        u16* __restrict__ og, u16* __restrict__ ou, u16* __restrict__ od) {
    int b = blockIdx.x;
    const float* src; u16* dst; int NT, KC, ROW;
    if (b < 2048)      { src = wgf; dst = og; NT = 16; KC = 16; ROW = FD; }
    else if (b < 4096) { b -= 2048; src = wuf; dst = ou; NT = 16; KC = 16; ROW = FD; }
    else               { b -= 4096; src = wdf; dst = od; NT = 8;  KC = 32; ROW = ED; }
    int kc = b % KC; int r = b / KC; int nt = r % NT; int e = r / NT;
    const float* base = src + (size_t)e * (size_t)(KC * 64) * ROW + (size_t)kc * 64 * ROW + nt * 128;
    u16* ob = dst + (size_t)b * 8192;

    int tid = threadIdx.x;
    int k0 = (tid & 7) * 8;
    int n0 = tid >> 3;
#pragma unroll
    for (int g4 = 0; g4 < 4; g4++) {
        int n = n0 + 32 * g4;
        const float* p = base + n;
        u32 w[4];
#pragma unroll
        for (int j = 0; j < 4; j++) {
            float a = p[(size_t)(k0 + 2 * j) * ROW];
            float c = p[(size_t)(k0 + 2 * j + 1) * ROW];
            w[j] = (u32)f2bf(a) | ((u32)f2bf(c) << 16);
        }
        *(u32v4*)(ob + (size_t)n * 64 + k0) = (u32v4){w[0], w[1], w[2], w[3]};
    }
}

// ---------------- pass A: gate+up GEMM, gelu*up, write act ----------------

__global__ __launch_bounds__(256, 2) void k_passA(
        const u16* __restrict__ xb, const u16* __restrict__ wg, const u16* __restrict__ wu,
        const int* __restrict__ cnt, const int* __restrict__ off,
        const int* __restrict__ tok, u16* __restrict__ act) {
    int e = blockIdx.z, mt = blockIdx.y, nt = blockIdx.x;
    int c = cnt[e];
    if (mt * BM >= c) return;
    int rmax = c - mt * BM; if (rmax > BM) rmax = BM;

    __shared__ u16 sA[BM * BK];
    __shared__ u16 sBg[BN * BK];
    __shared__ u16 sBu[BN * BK];

    int tid = threadIdx.x;
    int lane = tid & 63, wv = tid >> 6;
    int wm = wv >> 1, wn = wv & 1;
    int col = lane & 15, quad = lane >> 4;

    f32x4 zero = {0.f, 0.f, 0.f, 0.f};
    f32x4 ag[4][4], au[4][4];
#pragma unroll
    for (int i = 0; i < 4; i++)
#pragma unroll
        for (int j = 0; j < 4; j++) { ag[i][j] = zero; au[i][j] = zero; }

    // A staging: thread -> (row am, half ah), 32 elems per thread per chunk
    int am = tid >> 1, ah = tid & 1;
    int ridx = mt * BM + am; if (ridx > c - 1) ridx = c - 1;
    int trow = tok[e * NTOK + ridx];
    const u16* asrc = xb + (size_t)trow * ED + ah * 32;
    u16* adst = sA + am * BK + ah * 32;

    const u16* gg = wg + ((size_t)(e * 16 + nt) * 16) * 8192;
    const u16* gu = wu + ((size_t)(e * 16 + nt) * 16) * 8192;
    const u16* bsrc0 = (wv < 2 ? gg : gu);
    int bhalf = (wv & 1) * 4096;
    u16* bdst = (wv < 2 ? sBg : sBu) + bhalf;

    for (int kc = 0; kc < 16; kc++) {
        __syncthreads();
        const u16* bs = bsrc0 + (size_t)kc * 8192 + bhalf + lane * 8;
#pragma unroll
        for (int i = 0; i < 8; i++)
            gload16(bs + i * 512, bdst + i * 512);
        const u16* as = asrc + kc * 64;
        u32v4 v0 = *(const u32v4*)(as);
        u32v4 v1 = *(const u32v4*)(as + 8);
        u32v4 v2 = *(const u32v4*)(as + 16);
        u32v4 v3 = *(const u32v4*)(as + 24);
        *(u32v4*)(adst) = v0;
        *(u32v4*)(adst + 8) = v1;
        *(u32v4*)(adst + 16) = v2;
        *(u32v4*)(adst + 24) = v3;
        __syncthreads();
#pragma unroll
        for (int st = 0; st < 2; st++) {
            s16x8 af[4];
#pragma unroll
            for (int mf = 0; mf < 4; mf++)
                af[mf] = *(const s16x8*)(sA + (wm * 64 + mf * 16 + col) * BK + st * 32 + quad * 8);
#pragma unroll
            for (int nf = 0; nf < 4; nf++) {
                int brow = (wn * 64 + nf * 16 + col) * BK + st * 32 + quad * 8;
                s16x8 bg = *(const s16x8*)(sBg + brow);
                s16x8 bu = *(const s16x8*)(sBu + brow);
#pragma unroll
                for (int mf = 0; mf < 4; mf++) {
                    ag[mf][nf] = __builtin_amdgcn_mfma_f32_16x16x32_bf16(af[mf], bg, ag[mf][nf], 0, 0, 0);
                    au[mf][nf] = __builtin_amdgcn_mfma_f32_16x16x32_bf16(af[mf], bu, au[mf][nf], 0, 0, 0);
                }
            }
        }
    }

    // epilogue: act = gelu_tanh(gate) * up, store bf16 in passB A-fragment image order
    int tile = (off[e] >> 7) + mt;
    u16* ab = act + (size_t)tile * (32 * 8192);
#pragma unroll
    for (int mf = 0; mf < 4; mf++) {
#pragma unroll
        for (int reg = 0; reg < 4; reg++) {
            int m = wm * 64 + mf * 16 + quad * 4 + reg;
            if (m < rmax) {
#pragma unroll
                for (int nf = 0; nf < 4; nf++) {
                    float gv = ag[mf][nf][reg];
                    float uv = au[mf][nf][reg];
                    float z = 0.7978845608028654f * (gv + 0.044715f * gv * gv * gv);
                    float ez = __expf(-2.f * fabsf(z));
                    float th = (1.f - ez) / (1.f + ez);
                    th = (z < 0.f) ? -th : th;
                    float a = 0.5f * gv * (1.f + th) * uv;
                    int ng = nt * 128 + wn * 64 + nf * 16 + col;
                    ab[((size_t)(ng >> 6) * 128 + m) * 64 + (ng & 63)] = f2bf(a);
                }
            }
        }
    }
}

// ---------------- pass B: down GEMM + weighted scatter ----------------

__global__ __launch_bounds__(256, 3) void k_passB(
        const u16* __restrict__ act, const u16* __restrict__ wd,
        const int* __restrict__ cnt, const int* __restrict__ off,
        const int* __restrict__ tok, const float* __restrict__ wl,
        const float* __restrict__ scale, float* __restrict__ out) {
    int e = blockIdx.z, mt = blockIdx.y, nt = blockIdx.x;
    int c = cnt[e];
    if (mt * BM >= c) return;
    int rmax = c - mt * BM; if (rmax > BM) rmax = BM;

    __shared__ u16 sA[BM * BK];
    __shared__ u16 sB[BN * BK];

    int tid = threadIdx.x;
    int lane = tid & 63, wv = tid >> 6;
    int wm = wv >> 1, wn = wv & 1;
    int col = lane & 15, quad = lane >> 4;

    f32x4 zero = {0.f, 0.f, 0.f, 0.f};
    f32x4 acc[4][4];
#pragma unroll
    for (int i = 0; i < 4; i++)
#pragma unroll
        for (int j = 0; j < 4; j++) acc[i][j] = zero;

    int tile = (off[e] >> 7) + mt;
    const u16* ga = act + (size_t)tile * (32 * 8192);
    const u16* gb = wd + ((size_t)(e * 8 + nt) * 32) * 8192;
    const u16* src0 = (wv < 2 ? ga : gb);
    int shalf = (wv & 1) * 4096;
    u16* dst0 = (wv < 2 ? sA : sB) + shalf;

    for (int kc = 0; kc < 32; kc++) {
        __syncthreads();
        const u16* s = src0 + (size_t)kc * 8192 + shalf + lane * 8;
#pragma unroll
        for (int i = 0; i < 8; i++)
            gload16(s + i * 512, dst0 + i * 512);
        __syncthreads();
#pragma unroll
        for (int st = 0; st < 2; st++) {
            s16x8 af[4];
#pragma unroll
            for (int mf = 0; mf < 4; mf++)
                af[mf] = *(const s16x8*)(sA + (wm * 64 + mf * 16 + col) * BK + st * 32 + quad * 8);
#pragma unroll
            for (int nf = 0; nf < 4; nf++) {
                int brow = (wn * 64 + nf * 16 + col) * BK + st * 32 + quad * 8;
                s16x8 bf = *(const s16x8*)(sB + brow);
#pragma unroll
                for (int mf = 0; mf < 4; mf++)
                    acc[mf][nf] = __builtin_amdgcn_mfma_f32_16x16x32_bf16(af[mf], bf, acc[mf][nf], 0, 0, 0);
            }
        }
    }

    float sc = scale[e];
    int lbase = e * NTOK + mt * BM;
#pragma unroll
    for (int mf = 0; mf < 4; mf++) {
#pragma unroll
        for (int reg = 0; reg < 4; reg++) {
            int m = wm * 64 + mf * 16 + quad * 4 + reg;
            if (m < rmax) {
                int t = tok[lbase + m];
                float w = wl[lbase + m] * sc;
                float* orow = out + (size_t)t * ED + nt * 128 + wn * 64 + col;
#pragma unroll
                for (int nf = 0; nf < 4; nf++)
                    atomicAdd(orow + nf * 16, acc[mf][nf][reg] * w);
            }
        }
    }
}

// ---------------- launch ----------------

extern "C" void kernel_launch(void* const* d_in, const int* in_sizes, int n_in,
                              void* d_out, int out_size, void* d_ws, size_t ws_size,
                              hipStream_t stream) {
    const float* x   = (const float*)d_in[0];
    const float* gin = (const float*)d_in[1];
    const float* gk  = (const float*)d_in[2];
    const float* sc  = (const float*)d_in[3];
    const float* wgf = (const float*)d_in[4];
    const float* wuf = (const float*)d_in[5];
    const float* wdf = (const float*)d_in[6];
    float* out = (float*)d_out;

    if (ws_size < (size_t)WS_NEED) {
        // distinct failure signature: zero output (absmax == max|ref|)
        hipMemsetAsync(d_out, 0, (size_t)out_size * sizeof(float), stream);
        return;
    }

    char* ws = (char*)d_ws;
    int*   cnt = (int*)(ws + WS_CNT);
    int*   off = (int*)(ws + WS_OFF);
    int*   tok = (int*)(ws + WS_TOK);
    float* wl  = (float*)(ws + WS_WT);
    u16*   xb  = (u16*)(ws + WS_XB);
    u16*   og  = (u16*)(ws + WS_WG);
    u16*   ou  = (u16*)(ws + WS_WU);
    u16*   od  = (u16*)(ws + WS_WD);
    u16*   act = (u16*)(ws + WS_ACT);

    hipMemsetAsync(cnt, 0, 64, stream);
    hipMemsetAsync(d_out, 0, (size_t)out_size * sizeof(float), stream);

    k_router<<<dim3(512), dim3(256), 0, stream>>>(gin, gk, cnt, tok, wl);
    k_scan<<<dim3(1), dim3(64), 0, stream>>>(cnt, off);
    k_cvtx<<<dim3(2048), dim3(256), 0, stream>>>((const float4*)x, (uint2*)xb);
    k_cvtw<<<dim3(6144), dim3(256), 0, stream>>>(wgf, wuf, wdf, og, ou, od);
    k_passA<<<dim3(16, 16, NE), dim3(256), 0, stream>>>(xb, og, ou, cnt, off, tok, act);
    k_passB<<<dim3(8, 16, NE), dim3(256), 0, stream>>>(act, od, cnt, off, tok, wl, sc, out);
}

// Round 2
// 405.355 us; speedup vs baseline: 1.1160x; 1.1160x over previous
//
#include <hip/hip_runtime.h>
#include <math.h>
#include <stdint.h>

#define NE 8
#define ED 1024
#define FD 2048
#define NTOK 2048
#define BM 128
#define BN 128
#define BK 64

typedef unsigned short u16;
typedef unsigned int u32;
typedef __attribute__((ext_vector_type(4))) float f32x4;
typedef __attribute__((ext_vector_type(8))) short s16x8;
typedef __attribute__((ext_vector_type(4))) unsigned int u32v4;

// ---------------- helpers ----------------

__device__ __forceinline__ u16 f2bf(float f) {
    u32 u = __builtin_bit_cast(u32, f);
    u32 r = u + 0x7fffu + ((u >> 16) & 1u);   // RNE
    return (u16)(r >> 16);
}

typedef __attribute__((address_space(1))) const void gvoid_t;
typedef __attribute__((address_space(3))) void lvoid_t;

__device__ __forceinline__ void gload16(const void* g, void* l) {
    // async global->LDS, 16B per lane; LDS dest = uniform base + lane*16
    __builtin_amdgcn_global_load_lds((gvoid_t*)g, (lvoid_t*)l, 16, 0, 0);
}

// LDS tile swizzle: row r (64 u16 = 8 groups of 8), logical group g stored at
// physical group g ^ (r & 7). Baked into the GLOBAL weight/act images so the
// contiguous global_load_lds copy lands swizzled in LDS.

// workspace layout (bytes)
#define WS_CNT 0u
#define WS_OFF 64u
#define WS_TOK 256u
#define WS_WT  65792u
#define WS_XB  131328u
#define WS_WG  (8u << 20)
#define WS_WU  41943040u
#define WS_WD  75497472u
#define WS_ACT 109051904u
#define WS_NEED 130023424u

// ---------------- router ----------------

__global__ __launch_bounds__(256) void k_router(
        const float* __restrict__ gin, const float* __restrict__ gk,
        int* __restrict__ cnt, int* __restrict__ tok, float* __restrict__ wl) {
    int lane = threadIdx.x & 63;
    int t = (blockIdx.x * 256 + threadIdx.x) >> 6;   // one wave per token
    if (t >= NTOK) return;
    const float* row = gin + (size_t)t * ED;
    float acc[NE];
#pragma unroll
    for (int e = 0; e < NE; e++) acc[e] = 0.f;
    for (int i = lane; i < ED; i += 64) {
        float v = row[i];
        const float* g = gk + i * NE;
#pragma unroll
        for (int e = 0; e < NE; e++) acc[e] = fmaf(v, g[e], acc[e]);
    }
#pragma unroll
    for (int e = 0; e < NE; e++) {
#pragma unroll
        for (int off = 32; off > 0; off >>= 1)
            acc[e] += __shfl_down(acc[e], off, 64);
    }
    if (lane == 0) {
        int b0 = 0; float v0 = acc[0];
#pragma unroll
        for (int e = 1; e < NE; e++) if (acc[e] > v0) { v0 = acc[e]; b0 = e; }
        int b1 = -1; float v1 = -3.4e38f;
#pragma unroll
        for (int e = 0; e < NE; e++) if (e != b0 && acc[e] > v1) { v1 = acc[e]; b1 = e; }
        float w0 = 1.f / (1.f + __expf(-v0));
        float w1 = 1.f / (1.f + __expf(-v1));
        int p0 = atomicAdd(&cnt[b0], 1);
        tok[b0 * NTOK + p0] = t; wl[b0 * NTOK + p0] = w0;
        int p1 = atomicAdd(&cnt[b1], 1);
        tok[b1 * NTOK + p1] = t; wl[b1 * NTOK + p1] = w1;
    }
}

__global__ void k_scan(const int* __restrict__ cnt, int* __restrict__ off) {
    if (threadIdx.x == 0 && blockIdx.x == 0) {
        int a = 0;
#pragma unroll
        for (int e = 0; e < NE; e++) { off[e] = a; a += (cnt[e] + 127) & ~127; }
        off[NE] = a;
    }
}

// ---------------- x -> bf16 ----------------

__global__ __launch_bounds__(256) void k_cvtx(const float4* __restrict__ x, uint2* __restrict__ xb) {
    int i = blockIdx.x * 256 + threadIdx.x;   // over groups of 4 floats; total 524288
    float4 v = x[i];
    uint2 o;
    o.x = (u32)f2bf(v.x) | ((u32)f2bf(v.y) << 16);
    o.y = (u32)f2bf(v.z) | ((u32)f2bf(v.w) << 16);
    xb[i] = o;
}

// ---------------- weights f32 -> bf16, swizzled fragment-ordered tiles ------
// image per (e,nt,kc): 8192 elems, [n(128)][k(64)], n-major; 16B k-groups
// XOR-swizzled by (n&7). Coalesced reads via LDS transpose.

__global__ __launch_bounds__(256) void k_cvtw(
        const float* __restrict__ wgf, const float* __restrict__ wuf, const float* __restrict__ wdf,
        u16* __restrict__ og, u16* __restrict__ ou, u16* __restrict__ od) {
    int b = blockIdx.x;
    const float* src; u16* dst; int NT, KC, ROW;
    if (b < 2048)      { src = wgf; dst = og; NT = 16; KC = 16; ROW = FD; }
    else if (b < 4096) { b -= 2048; src = wuf; dst = ou; NT = 16; KC = 16; ROW = FD; }
    else               { b -= 4096; src = wdf; dst = od; NT = 8;  KC = 32; ROW = ED; }
    int kc = b % KC; int r = b / KC; int nt = r % NT; int e = r / NT;
    const float* base = src + (size_t)e * (size_t)(KC * 64) * ROW + (size_t)kc * 64 * ROW + nt * 128;
    u16* ob = dst + (size_t)(blockIdx.x < 2048 ? blockIdx.x :
                             (blockIdx.x < 4096 ? blockIdx.x - 2048 : blockIdx.x - 4096)) * 8192;

    __shared__ float sl[64 * 129];   // stride 129 (odd) -> 2-way max on both phases
    int tid = threadIdx.x;

    // stage 1: coalesced read [k][n] -> LDS
    {
        int k = tid >> 2, q = tid & 3;
        const float* rp = base + (size_t)k * ROW;
        float* lp = sl + k * 129;
#pragma unroll
        for (int j = 0; j < 8; j++) {
            int n0 = (q + 4 * j) * 4;     // lanes of a quad cover 64B contiguous
            float4 v = *(const float4*)(rp + n0);
            lp[n0] = v.x; lp[n0 + 1] = v.y; lp[n0 + 2] = v.z; lp[n0 + 3] = v.w;
        }
    }
    __syncthreads();

    // stage 2: transpose + convert + swizzle, contiguous 16B/lane global writes
#pragma unroll
    for (int jg = 0; jg < 4; jg++) {
        int v = tid + 256 * jg;           // 0..1023 vec slots
        int n = v >> 3, p = v & 7;        // physical group p
        int k0 = (p ^ (n & 7)) * 8;       // logical k-group
        u32 w[4];
#pragma unroll
        for (int u = 0; u < 4; u++) {
            float a = sl[(k0 + 2 * u) * 129 + n];
            float c = sl[(k0 + 2 * u + 1) * 129 + n];
            w[u] = (u32)f2bf(a) | ((u32)f2bf(c) << 16);
        }
        *(u32v4*)(ob + (size_t)n * 64 + p * 8) = (u32v4){w[0], w[1], w[2], w[3]};
    }
}

// ---------------- pass A: gate+up GEMM, gelu*up, write act ----------------

__global__ __launch_bounds__(256, 2) void k_passA(
        const u16* __restrict__ xb, const u16* __restrict__ wg, const u16* __restrict__ wu,
        const int* __restrict__ cnt, const int* __restrict__ off,
        const int* __restrict__ tok, u16* __restrict__ act) {
    int e = blockIdx.z, mt = blockIdx.y, nt = blockIdx.x;
    int c = cnt[e];
    if (mt * BM >= c) return;
    int rmax = c - mt * BM; if (rmax > BM) rmax = BM;

    __shared__ u16 sA[BM * BK];
    __shared__ u16 sBg[BN * BK];
    __shared__ u16 sBu[BN * BK];

    int tid = threadIdx.x;
    int lane = tid & 63, wv = tid >> 6;
    int wm = wv >> 1, wn = wv & 1;
    int col = lane & 15, quad = lane >> 4;
    int swz = col & 7;

    f32x4 zero = {0.f, 0.f, 0.f, 0.f};
    f32x4 ag[4][4], au[4][4];
#pragma unroll
    for (int i = 0; i < 4; i++)
#pragma unroll
        for (int j = 0; j < 4; j++) { ag[i][j] = zero; au[i][j] = zero; }

    // A staging: thread -> (row am, half ah), 32 elems per thread per chunk
    int am = tid >> 1, ah = tid & 1;
    int ridx = mt * BM + am; if (ridx > c - 1) ridx = c - 1;
    int trow = tok[e * NTOK + ridx];
    const u16* asrc = xb + (size_t)trow * ED + ah * 32;
    u16* adst = sA + am * BK;

    const u16* gg = wg + ((size_t)(e * 16 + nt) * 16) * 8192;
    const u16* gu = wu + ((size_t)(e * 16 + nt) * 16) * 8192;
    const u16* bsrc0 = (wv < 2 ? gg : gu);
    int bhalf = (wv & 1) * 4096;
    u16* bdst = (wv < 2 ? sBg : sBu) + bhalf;

    for (int kc = 0; kc < 16; kc++) {
        __syncthreads();
        const u16* bs = bsrc0 + (size_t)kc * 8192 + bhalf + lane * 8;
#pragma unroll
        for (int i = 0; i < 8; i++)
            gload16(bs + i * 512, bdst + i * 512);
        const u16* as = asrc + kc * 64;
#pragma unroll
        for (int j = 0; j < 4; j++) {
            int pg = (ah * 4 + j) ^ (am & 7);       // swizzled physical group
            *(u32v4*)(adst + pg * 8) = *(const u32v4*)(as + j * 8);
        }
        __syncthreads();
#pragma unroll
        for (int st = 0; st < 2; st++) {
            int poff = ((st * 4 + quad) ^ swz) * 8;  // swizzled fragment offset
            s16x8 af[4];
#pragma unroll
            for (int mf = 0; mf < 4; mf++)
                af[mf] = *(const s16x8*)(sA + (wm * 64 + mf * 16 + col) * BK + poff);
#pragma unroll
            for (int nf = 0; nf < 4; nf++) {
                int brow = (wn * 64 + nf * 16 + col) * BK + poff;
                s16x8 bg = *(const s16x8*)(sBg + brow);
                s16x8 bu = *(const s16x8*)(sBu + brow);
#pragma unroll
                for (int mf = 0; mf < 4; mf++) {
                    ag[mf][nf] = __builtin_amdgcn_mfma_f32_16x16x32_bf16(af[mf], bg, ag[mf][nf], 0, 0, 0);
                    au[mf][nf] = __builtin_amdgcn_mfma_f32_16x16x32_bf16(af[mf], bu, au[mf][nf], 0, 0, 0);
                }
            }
        }
    }

    // epilogue: act = gelu_tanh(gate) * up, store bf16 into swizzled passB A-images
    int tile = (off[e] >> 7) + mt;
    u16* ab = act + (size_t)tile * (32 * 8192);
#pragma unroll
    for (int mf = 0; mf < 4; mf++) {
#pragma unroll
        for (int reg = 0; reg < 4; reg++) {
            int m = wm * 64 + mf * 16 + quad * 4 + reg;
            if (m < rmax) {
#pragma unroll
                for (int nf = 0; nf < 4; nf++) {
                    float gv = ag[mf][nf][reg];
                    float uv = au[mf][nf][reg];
                    float z = 0.7978845608028654f * (gv + 0.044715f * gv * gv * gv);
                    float ez = __expf(-2.f * fabsf(z));
                    float th = (1.f - ez) / (1.f + ez);
                    th = (z < 0.f) ? -th : th;
                    float a = 0.5f * gv * (1.f + th) * uv;
                    int ng = nt * 128 + wn * 64 + nf * 16 + col;
                    int pos = ((((ng >> 3) & 7) ^ (m & 7)) * 8) | (ng & 7);
                    ab[(size_t)(ng >> 6) * 8192 + (size_t)m * 64 + pos] = f2bf(a);
                }
            }
        }
    }
}

// ---------------- pass B: down GEMM + weighted scatter ----------------

__global__ __launch_bounds__(256, 3) void k_passB(
        const u16* __restrict__ act, const u16* __restrict__ wd,
        const int* __restrict__ cnt, const int* __restrict__ off,
        const int* __restrict__ tok, const float* __restrict__ wl,
        const float* __restrict__ scale, float* __restrict__ out) {
    int e = blockIdx.z, mt = blockIdx.y, nt = blockIdx.x;
    int c = cnt[e];
    if (mt * BM >= c) return;
    int rmax = c - mt * BM; if (rmax > BM) rmax = BM;

    __shared__ u16 sA[BM * BK];
    __shared__ u16 sB[BN * BK];

    int tid = threadIdx.x;
    int lane = tid & 63, wv = tid >> 6;
    int wm = wv >> 1, wn = wv & 1;
    int col = lane & 15, quad = lane >> 4;
    int swz = col & 7;

    f32x4 zero = {0.f, 0.f, 0.f, 0.f};
    f32x4 acc[4][4];
#pragma unroll
    for (int i = 0; i < 4; i++)
#pragma unroll
        for (int j = 0; j < 4; j++) acc[i][j] = zero;

    int tile = (off[e] >> 7) + mt;
    const u16* ga = act + (size_t)tile * (32 * 8192);
    const u16* gb = wd + ((size_t)(e * 8 + nt) * 32) * 8192;
    const u16* src0 = (wv < 2 ? ga : gb);
    int shalf = (wv & 1) * 4096;
    u16* dst0 = (wv < 2 ? sA : sB) + shalf;

    for (int kc = 0; kc < 32; kc++) {
        __syncthreads();
        const u16* s = src0 + (size_t)kc * 8192 + shalf + lane * 8;
#pragma unroll
        for (int i = 0; i < 8; i++)
            gload16(s + i * 512, dst0 + i * 512);
        __syncthreads();
#pragma unroll
        for (int st = 0; st < 2; st++) {
            int poff = ((st * 4 + quad) ^ swz) * 8;
            s16x8 af[4];
#pragma unroll
            for (int mf = 0; mf < 4; mf++)
                af[mf] = *(const s16x8*)(sA + (wm * 64 + mf * 16 + col) * BK + poff);
#pragma unroll
            for (int nf = 0; nf < 4; nf++) {
                int brow = (wn * 64 + nf * 16 + col) * BK + poff;
                s16x8 bf = *(const s16x8*)(sB + brow);
#pragma unroll
                for (int mf = 0; mf < 4; mf++)
                    acc[mf][nf] = __builtin_amdgcn_mfma_f32_16x16x32_bf16(af[mf], bf, acc[mf][nf], 0, 0, 0);
            }
        }
    }

    float sc = scale[e];
    int lbase = e * NTOK + mt * BM;
#pragma unroll
    for (int mf = 0; mf < 4; mf++) {
#pragma unroll
        for (int reg = 0; reg < 4; reg++) {
            int m = wm * 64 + mf * 16 + quad * 4 + reg;
            if (m < rmax) {
                int t = tok[lbase + m];
                float w = wl[lbase + m] * sc;
                float* orow = out + (size_t)t * ED + nt * 128 + wn * 64 + col;
#pragma unroll
                for (int nf = 0; nf < 4; nf++)
                    atomicAdd(orow + nf * 16, acc[mf][nf][reg] * w);
            }
        }
    }
}

// ---------------- launch ----------------

extern "C" void kernel_launch(void* const* d_in, const int* in_sizes, int n_in,
                              void* d_out, int out_size, void* d_ws, size_t ws_size,
                              hipStream_t stream) {
    const float* x   = (const float*)d_in[0];
    const float* gin = (const float*)d_in[1];
    const float* gk  = (const float*)d_in[2];
    const float* sc  = (const float*)d_in[3];
    const float* wgf = (const float*)d_in[4];
    const float* wuf = (const float*)d_in[5];
    const float* wdf = (const float*)d_in[6];
    float* out = (float*)d_out;

    if (ws_size < (size_t)WS_NEED) {
        hipMemsetAsync(d_out, 0, (size_t)out_size * sizeof(float), stream);
        return;
    }

    char* ws = (char*)d_ws;
    int*   cnt = (int*)(ws + WS_CNT);
    int*   off = (int*)(ws + WS_OFF);
    int*   tok = (int*)(ws + WS_TOK);
    float* wl  = (float*)(ws + WS_WT);
    u16*   xb  = (u16*)(ws + WS_XB);
    u16*   og  = (u16*)(ws + WS_WG);
    u16*   ou  = (u16*)(ws + WS_WU);
    u16*   od  = (u16*)(ws + WS_WD);
    u16*   act = (u16*)(ws + WS_ACT);

    hipMemsetAsync(cnt, 0, 64, stream);
    hipMemsetAsync(d_out, 0, (size_t)out_size * sizeof(float), stream);

    k_router<<<dim3(512), dim3(256), 0, stream>>>(gin, gk, cnt, tok, wl);
    k_scan<<<dim3(1), dim3(64), 0, stream>>>(cnt, off);
    k_cvtx<<<dim3(2048), dim3(256), 0, stream>>>((const float4*)x, (uint2*)xb);
    k_cvtw<<<dim3(6144), dim3(256), 0, stream>>>(wgf, wuf, wdf, og, ou, od);
    k_passA<<<dim3(16, 16, NE), dim3(256), 0, stream>>>(xb, og, ou, cnt, off, tok, act);
    k_passB<<<dim3(8, 16, NE), dim3(256), 0, stream>>>(act, od, cnt, off, tok, wl, sc, out);
}